// Round 6
// baseline (475.842 us; speedup 1.0000x reference)
//
#include <hip/hip_runtime.h>

// int4-dequant GEMM: y[m,n] = sum_k x[m,k] * scale[n, k/128] * (q[n,k] - 8)
// x: (512,4096) f32 | weight_packed: (11008,2048) int32 (2 nibbles in low byte) |
// scales: (11008,32) f32 | out: (512,11008) f32
//
// R6: R5 tile structure (256x128 block, 128x64 wave, 32x32x16 MFMA, split-K x4)
// with the three R5 sins fixed:
//  - atomics -> coalesced f32 partials in ws + counter-gated last-block reduce
//  - no pipeline -> register prefetch of next tile across the MFMA section
//  - 14-op dequant -> v_cvt_pk_bf16_f32 (gfx950) when available

typedef __attribute__((ext_vector_type(8)))  short short8;   // 32x32x16 A/B frag
typedef __attribute__((ext_vector_type(16))) float f32x16;   // 32x32x16 C/D frag
typedef __attribute__((ext_vector_type(4)))  float f32x4;
typedef __attribute__((ext_vector_type(4)))  int   i32x4;
typedef __attribute__((ext_vector_type(2)))  int   i32x2;

#define M_DIM 512
#define N_DIM 11008
#define K_DIM 4096
#define BM 256
#define BN 128
#define BK 64
#define PAD 8            // row stride 144B: conflict-free (R5 measured 0 conflicts)
#define THREADS 256
#define NTILE_M (M_DIM / BM)        // 2
#define NTILE_N (N_DIM / BN)        // 86
#define TILE_ELEMS (BM * BN)        // 32768

#if defined(__has_builtin)
#  if __has_builtin(__builtin_amdgcn_cvt_pk_bf16_f32)
#    define HAVE_PK_BF16 1
#  endif
#endif
#ifndef HAVE_PK_BF16
#  define HAVE_PK_BF16 0
#endif

__device__ __forceinline__ unsigned int fbits(float f) {
    union { float f; unsigned int u; } c; c.f = f; return c.u;
}
__device__ __forceinline__ unsigned int f2bf(float f) {   // RNE, finite-only
    unsigned int u = fbits(f);
    return (u + 0x7FFFu + ((u >> 16) & 1u)) >> 16;
}
__device__ __forceinline__ int pack2bf(float lo, float hi) {  // [hi|lo] bf16 pair
#if HAVE_PK_BF16
    typedef __attribute__((ext_vector_type(2))) __bf16 bf16x2;
    bf16x2 p = __builtin_amdgcn_cvt_pk_bf16_f32(lo, hi);
    int r; __builtin_memcpy(&r, &p, 4);
    return r;
#else
    unsigned int ul = fbits(lo), uh = fbits(hi);
    unsigned int l = (ul + 0x7FFFu + ((ul >> 16) & 1u)) >> 16;
    unsigned int h = (uh + 0x7FFFu + ((uh >> 16) & 1u)) & 0xFFFF0000u;
    return (int)(h | l);
#endif
}

// ---- x f32 -> bf16 workspace ----
__global__ __launch_bounds__(THREADS)
void cvt_x(const float* __restrict__ x, unsigned short* __restrict__ xw)
{
    int idx = (blockIdx.x * THREADS + threadIdx.x) * 4;
    f32x4 v = *(const f32x4*)(x + idx);
    i32x2 p;
    p[0] = pack2bf(v[0], v[1]);
    p[1] = pack2bf(v[2], v[3]);
    *(i32x2*)(xw + idx) = p;
}

// ---- main GEMM ----
template<int KS, bool PRECVT>
__global__ __launch_bounds__(THREADS, 2)
void dq_gemm(const unsigned short* __restrict__ xw,
             const float* __restrict__ xf,
             const int* __restrict__ wp,
             const float* __restrict__ scales,
             float* __restrict__ out,
             float* __restrict__ partials,
             int* __restrict__ counters)
{
    __shared__ __align__(16) unsigned short sA[BM][BK + PAD];  // 36.9 KB
    __shared__ __align__(16) unsigned short sB[BN][BK + PAD];  // 18.4 KB
    __shared__ int s_last;

    const int t  = threadIdx.x;
    const int bx = blockIdx.x;

    int m_idx, nb, ksp;
    if (KS == 4) {
        // ids differing by 8 (same XCD, %8 round-robin) = the two m-blocks of one (n,ks)
        m_idx = (bx >> 3) & 1;
        int rest = (bx & 7) | ((bx >> 4) << 3);   // [0, 344)
        ksp = rest & 3;
        nb  = rest >> 2;
    } else {
        m_idx = bx & 1;
        nb  = bx >> 1;
        ksp = 0;
    }
    const int m0 = m_idx * BM;
    const int n0 = nb * BN;
    const int k0 = ksp * (K_DIM / KS);
    const int KITERS = (K_DIM / KS) / BK;         // 16 (KS=4) / 64 (KS=1)

    const int wave = t >> 6;
    const int lane = t & 63;
    const int wm = (wave & 1) * 128;
    const int wn = (wave >> 1) * 64;
    const int lr = lane & 31;          // frag row
    const int lk = (lane >> 5) * 8;    // frag k

    f32x16 acc[4][2] = {};             // wave tile 128x64

    // prefetch registers
    i32x4 pa[PRECVT ? 8 : 1];
    i32x4 pb[4];
    float psc[4];

    auto load_tile = [&](int kb) {
        if constexpr (PRECVT) {
            #pragma unroll
            for (int i = 0; i < 8; ++i) {
                int c = i * 256 + t, row = c >> 3, col = (c & 7) * 8;
                pa[i] = *(const i32x4*)(xw + (size_t)(m0 + row) * K_DIM + kb + col);
            }
        }
        const int g = kb >> 7;
        #pragma unroll
        for (int i = 0; i < 4; ++i) {
            int c = i * 256 + t, row = c >> 3, ic = (c & 7) * 4;
            pb[i]  = *(const i32x4*)(wp + (size_t)(n0 + row) * (K_DIM / 2) + (kb >> 1) + ic);
            psc[i] = scales[(size_t)(n0 + row) * (K_DIM / 128) + g];
        }
    };

    auto store_tile = [&](int kb) {
        if constexpr (PRECVT) {
            #pragma unroll
            for (int i = 0; i < 8; ++i) {
                int c = i * 256 + t, row = c >> 3, col = (c & 7) * 8;
                *(i32x4*)&sA[row][col] = pa[i];
            }
        } else {
            #pragma unroll
            for (int i = 0; i < 16; ++i) {          // unpipelined fallback path
                int c = i * 256 + t, row = c >> 4, col = (c & 15) * 4;
                f32x4 v = *(const f32x4*)(xf + (size_t)(m0 + row) * K_DIM + kb + col);
                i32x2 p;
                p[0] = pack2bf(v[0], v[1]);
                p[1] = pack2bf(v[2], v[3]);
                *(i32x2*)&sA[row][col] = p;
            }
        }
        #pragma unroll
        for (int i = 0; i < 4; ++i) {
            int c = i * 256 + t, row = c >> 3, ic = (c & 7) * 4;
            float s  = psc[i];
            float ns8 = s * -8.0f;
            i32x4 res;
            #pragma unroll
            for (int e = 0; e < 4; ++e) {
                int b = pb[i][e];
                float flo = (float)(b & 15) * s + ns8;
                float fhi = (float)((b >> 4) & 15) * s + ns8;
                res[e] = pack2bf(flo, fhi);
            }
            *(i32x4*)&sB[row][ic * 2] = res;
        }
    };

    // ---- prologue ----
    load_tile(k0);
    store_tile(k0);
    __syncthreads();

    int kb = k0;
    for (int kk = 0; kk < KITERS; ++kk) {
        const bool has_next = (kk + 1 < KITERS);
        if (has_next) load_tile(kb + BK);     // in flight across the MFMA section

        #pragma unroll
        for (int ks = 0; ks < BK; ks += 16) {
            short8 a[4], b[2];
            #pragma unroll
            for (int i = 0; i < 4; ++i)
                a[i] = *(const short8*)&sA[wm + i * 32 + lr][ks + lk];
            #pragma unroll
            for (int j = 0; j < 2; ++j)
                b[j] = *(const short8*)&sB[wn + j * 32 + lr][ks + lk];
            #pragma unroll
            for (int i = 0; i < 4; ++i)
                #pragma unroll
                for (int j = 0; j < 2; ++j)
                    acc[i][j] = __builtin_amdgcn_mfma_f32_32x32x16_bf16(
                        a[i], b[j], acc[i][j], 0, 0, 0);
        }

        __syncthreads();                       // everyone done reading LDS
        if (has_next) {
            store_tile(kb + BK);               // waits vmcnt here (hidden by MFMA above)
            __syncthreads();                   // next tile ready
        }
        kb += BK;
    }

    // ---- epilogue ----
    const int rbase = (lane >> 5) * 4;
    if constexpr (KS == 1) {
        // direct store: C/D col=lane&31, row=(r&3)+8*(r>>2)+4*(lane>>5)
        #pragma unroll
        for (int i = 0; i < 4; ++i) {
            int mg0 = m0 + wm + i * 32 + rbase;
            #pragma unroll
            for (int j = 0; j < 2; ++j) {
                int ng = n0 + wn + j * 32 + lr;
                #pragma unroll
                for (int r = 0; r < 16; ++r)
                    out[(size_t)(mg0 + (r & 3) + 8 * (r >> 2)) * N_DIM + ng] = acc[i][j][r];
            }
        }
    } else {
        const int tid = m_idx * NTILE_N + nb;            // output tile id [0,172)
        // coalesced per-lane-slot partial store: slot = t*128 + (i*2+j)*16 + q*4 + rr
        float* my = partials + ((size_t)tid * KS + ksp) * TILE_ELEMS + t * 128;
        #pragma unroll
        for (int i = 0; i < 4; ++i)
            #pragma unroll
            for (int j = 0; j < 2; ++j)
                #pragma unroll
                for (int q = 0; q < 4; ++q) {
                    f32x4 v;
                    v[0] = acc[i][j][q * 4 + 0];
                    v[1] = acc[i][j][q * 4 + 1];
                    v[2] = acc[i][j][q * 4 + 2];
                    v[3] = acc[i][j][q * 4 + 3];
                    *(f32x4*)(my + (i * 2 + j) * 16 + q * 4) = v;
                }
        __threadfence();                                  // release partials device-wide
        __syncthreads();
        if (t == 0)
            s_last = (atomicAdd(&counters[tid], 1) == KS - 1);
        __syncthreads();
        if (s_last) {
            __threadfence();                              // acquire
            const float* pbase = partials + (size_t)tid * KS * TILE_ELEMS + t * 128;
            #pragma unroll
            for (int i = 0; i < 4; ++i) {
                #pragma unroll
                for (int j = 0; j < 2; ++j) {
                    int ng = n0 + wn + j * 32 + lr;
                    #pragma unroll
                    for (int q = 0; q < 4; ++q) {
                        int off = (i * 2 + j) * 16 + q * 4;
                        f32x4 sum = *(const f32x4*)(pbase + off);
                        #pragma unroll
                        for (int p = 1; p < KS; ++p)
                            sum += *(const f32x4*)(pbase + p * TILE_ELEMS + off);
                        int mg = m0 + wm + i * 32 + rbase + 8 * q;
                        #pragma unroll
                        for (int rr = 0; rr < 4; ++rr)
                            out[(size_t)(mg + rr) * N_DIM + ng] = sum[rr];
                    }
                }
            }
        }
    }
}

extern "C" void kernel_launch(void* const* d_in, const int* in_sizes, int n_in,
                              void* d_out, int out_size, void* d_ws, size_t ws_size,
                              hipStream_t stream) {
    (void)in_sizes; (void)n_in; (void)out_size;
    const float* x      = (const float*)d_in[0];
    const int*   wpck   = (const int*)d_in[1];
    const float* scales = (const float*)d_in[2];
    float*       out    = (float*)d_out;

    const size_t XW_BYTES   = (size_t)M_DIM * K_DIM * 2;                       // 4 MB
    const size_t CNT_OFF    = XW_BYTES;
    const size_t CNT_BYTES  = (size_t)NTILE_M * NTILE_N * 4;                   // 688 B
    const size_t PART_OFF   = XW_BYTES + 4096;
    const size_t PART_BYTES = (size_t)NTILE_M * NTILE_N * 4 * TILE_ELEMS * 4;  // 90.2 MB

    if (ws_size >= PART_OFF + PART_BYTES) {
        unsigned short* xw  = (unsigned short*)d_ws;
        int*   cnt  = (int*)((char*)d_ws + CNT_OFF);
        float* part = (float*)((char*)d_ws + PART_OFF);
        hipMemsetAsync(cnt, 0, CNT_BYTES, stream);
        cvt_x<<<(M_DIM * K_DIM) / (THREADS * 4), THREADS, 0, stream>>>(x, xw);
        dq_gemm<4, true><<<NTILE_M * NTILE_N * 4, THREADS, 0, stream>>>(
            xw, x, wpck, scales, out, part, cnt);
    } else if (ws_size >= XW_BYTES) {
        unsigned short* xw = (unsigned short*)d_ws;
        cvt_x<<<(M_DIM * K_DIM) / (THREADS * 4), THREADS, 0, stream>>>(x, xw);
        dq_gemm<1, true><<<NTILE_M * NTILE_N, THREADS, 0, stream>>>(
            xw, x, wpck, scales, out, nullptr, nullptr);
    } else {
        dq_gemm<1, false><<<NTILE_M * NTILE_N, THREADS, 0, stream>>>(
            nullptr, x, wpck, scales, out, nullptr, nullptr);
    }
}

// Round 7
// 221.094 us; speedup vs baseline: 2.1522x; 2.1522x over previous
//
#include <hip/hip_runtime.h>

// int4-dequant GEMM: y[m,n] = sum_k x[m,k] * scale[n, k/128] * (q[n,k] - 8)
// x: (512,4096) f32 | weight_packed: (11008,2048) int32 (2 nibbles in low byte) |
// scales: (11008,32) f32 | out: (512,11008) f32
//
// R7: R5's proven K-loop (NO register prefetch: R6 proved 128 AGPR acc + prefetch
// regs = spill at 2 waves/SIMD) + split-K partials with lane-coalesced layout +
// separate reduce kernel (no atomics: R5 showed ~100us atomic cost; no in-kernel
// fence/counter reduce: R6 tail).

typedef __attribute__((ext_vector_type(8)))  short short8;   // 32x32x16 A/B frag
typedef __attribute__((ext_vector_type(16))) float f32x16;   // 32x32x16 C/D frag
typedef __attribute__((ext_vector_type(4)))  float f32x4;
typedef __attribute__((ext_vector_type(4)))  int   i32x4;
typedef __attribute__((ext_vector_type(2)))  int   i32x2;

#define M_DIM 512
#define N_DIM 11008
#define K_DIM 4096
#define BM 256
#define BN 128
#define BK 64
#define KSPLIT 4
#define PAD 8            // row stride 144B: measured 0 conflicts (R5)
#define THREADS 256
#define NTILE_M (M_DIM / BM)        // 2
#define NTILE_N (N_DIM / BN)        // 86
#define NTILES  (NTILE_M * NTILE_N) // 172
#define TILE_ELEMS (BM * BN)        // 32768

#if defined(__has_builtin)
#  if __has_builtin(__builtin_amdgcn_cvt_pk_bf16_f32)
#    define HAVE_PK_BF16 1
#  endif
#endif
#ifndef HAVE_PK_BF16
#  define HAVE_PK_BF16 0
#endif

__device__ __forceinline__ unsigned int fbits(float f) {
    union { float f; unsigned int u; } c; c.f = f; return c.u;
}
__device__ __forceinline__ int pack2bf(float lo, float hi) {  // [hi|lo] bf16, RNE
#if HAVE_PK_BF16
    typedef __attribute__((ext_vector_type(2))) __bf16 bf16x2;
    bf16x2 p = __builtin_amdgcn_cvt_pk_bf16_f32(lo, hi);
    int r; __builtin_memcpy(&r, &p, 4);
    return r;
#else
    unsigned int ul = fbits(lo), uh = fbits(hi);
    unsigned int l = (ul + 0x7FFFu + ((ul >> 16) & 1u)) >> 16;
    unsigned int h = (uh + 0x7FFFu + ((uh >> 16) & 1u)) & 0xFFFF0000u;
    return (int)(h | l);
#endif
}

// ---- x f32 -> bf16 workspace ----
__global__ __launch_bounds__(THREADS)
void cvt_x(const float* __restrict__ x, unsigned short* __restrict__ xw)
{
    int idx = (blockIdx.x * THREADS + threadIdx.x) * 4;
    f32x4 v = *(const f32x4*)(x + idx);
    i32x2 p;
    p[0] = pack2bf(v[0], v[1]);
    p[1] = pack2bf(v[2], v[3]);
    *(i32x2*)(xw + idx) = p;
}

// ---- main GEMM: 256x128 tile, 4 waves of 128x64, 32x32x16 MFMA ----
template<int KS, bool PRECVT>
__global__ __launch_bounds__(THREADS, 2)
void dq_gemm(const unsigned short* __restrict__ xw,
             const float* __restrict__ xf,
             const int* __restrict__ wp,
             const float* __restrict__ scales,
             float* __restrict__ out,
             float* __restrict__ partials)
{
    __shared__ __align__(16) unsigned short sA[BM][BK + PAD];  // 36.9 KB
    __shared__ __align__(16) unsigned short sB[BN][BK + PAD];  // 18.4 KB

    const int t  = threadIdx.x;
    const int bx = blockIdx.x;

    int m_idx, nb, ksp;
    if (KS == 4) {
        // bx and bx+8 land on the same XCD (%8 round-robin): pair the two
        // m-blocks of one (n,ksp) for weight L2 reuse.
        m_idx = (bx >> 3) & 1;
        int rest = (bx & 7) | ((bx >> 4) << 3);   // [0, 344)
        ksp = rest & 3;
        nb  = rest >> 2;
    } else {
        m_idx = bx & 1;
        nb  = bx >> 1;
        ksp = 0;
    }
    const int m0 = m_idx * BM;
    const int n0 = nb * BN;
    const int k0 = ksp * (K_DIM / KS);
    const int KITERS = (K_DIM / KS) / BK;

    const int wave = t >> 6;
    const int lane = t & 63;
    const int wm = (wave & 1) * 128;
    const int wn = (wave >> 1) * 64;
    const int lr = lane & 31;          // frag row
    const int lk = (lane >> 5) * 8;    // frag k

    f32x16 acc[4][2] = {};

    for (int kk = 0; kk < KITERS; ++kk) {
        const int kb = k0 + kk * BK;
        const int g  = kb >> 7;

        // ---- stage A: 256x64 bf16, 8 x 16B chunks/thread ----
        if constexpr (PRECVT) {
            #pragma unroll
            for (int i = 0; i < 8; ++i) {
                int c = i * 256 + t, row = c >> 3, col = (c & 7) * 8;
                *(i32x4*)&sA[row][col] =
                    *(const i32x4*)(xw + (size_t)(m0 + row) * K_DIM + kb + col);
            }
        } else {
            #pragma unroll
            for (int i = 0; i < 16; ++i) {
                int c = i * 256 + t, row = c >> 4, col = (c & 15) * 4;
                f32x4 v = *(const f32x4*)(xf + (size_t)(m0 + row) * K_DIM + kb + col);
                i32x2 p;
                p[0] = pack2bf(v[0], v[1]);
                p[1] = pack2bf(v[2], v[3]);
                *(i32x2*)&sA[row][col] = p;
            }
        }

        // ---- stage B: 128 rows x 32 ints, dequant -> bf16, 4 chunks/thread ----
        #pragma unroll
        for (int i = 0; i < 4; ++i) {
            int c = i * 256 + t, row = c >> 3, ic = (c & 7) * 4;
            i32x4 pv = *(const i32x4*)(wp + (size_t)(n0 + row) * (K_DIM / 2) + (kb >> 1) + ic);
            float s  = scales[(size_t)(n0 + row) * (K_DIM / 128) + g];
            float ns8 = s * -8.0f;
            i32x4 res;
            #pragma unroll
            for (int e = 0; e < 4; ++e) {
                int b = pv[e];
                res[e] = pack2bf((float)(b & 15) * s + ns8,
                                 (float)((b >> 4) & 15) * s + ns8);
            }
            *(i32x4*)&sB[row][ic * 2] = res;
        }

        __syncthreads();

        #pragma unroll
        for (int ks = 0; ks < BK; ks += 16) {
            short8 a[4], b[2];
            #pragma unroll
            for (int i = 0; i < 4; ++i)
                a[i] = *(const short8*)&sA[wm + i * 32 + lr][ks + lk];
            #pragma unroll
            for (int j = 0; j < 2; ++j)
                b[j] = *(const short8*)&sB[wn + j * 32 + lr][ks + lk];
            #pragma unroll
            for (int i = 0; i < 4; ++i)
                #pragma unroll
                for (int j = 0; j < 2; ++j)
                    acc[i][j] = __builtin_amdgcn_mfma_f32_32x32x16_bf16(
                        a[i], b[j], acc[i][j], 0, 0, 0);
        }

        __syncthreads();
    }

    const int rbase = (lane >> 5) * 4;
    if constexpr (KS == 1) {
        // direct store: C/D col=lane&31, row=(r&3)+8*(r>>2)+4*(lane>>5)
        #pragma unroll
        for (int i = 0; i < 4; ++i) {
            int mg0 = m0 + wm + i * 32 + rbase;
            #pragma unroll
            for (int j = 0; j < 2; ++j) {
                int ng = n0 + wn + j * 32 + lr;
                #pragma unroll
                for (int r = 0; r < 16; ++r)
                    out[(size_t)(mg0 + (r & 3) + 8 * (r >> 2)) * N_DIM + ng] = acc[i][j][r];
            }
        }
    } else {
        // lane-coalesced partial store: float index = c*1024 + t*4 + rr,
        // c = (i*2+j)*4 + q. Each dwordx4 store is lane-contiguous.
        float* my = partials + ((size_t)(m_idx * NTILE_N + nb) * KS + ksp) * TILE_ELEMS;
        #pragma unroll
        for (int i = 0; i < 4; ++i)
            #pragma unroll
            for (int j = 0; j < 2; ++j)
                #pragma unroll
                for (int q = 0; q < 4; ++q) {
                    int c = (i * 2 + j) * 4 + q;
                    f32x4 v;
                    v[0] = acc[i][j][q * 4 + 0];
                    v[1] = acc[i][j][q * 4 + 1];
                    v[2] = acc[i][j][q * 4 + 2];
                    v[3] = acc[i][j][q * 4 + 3];
                    *(f32x4*)(my + c * 1024 + t * 4) = v;
                }
    }
}

// ---- reduce: sum 4 partials, frag-slot -> row-major via LDS, coalesced out ----
// 344 blocks: block b handles m-half h of tile b>>1 (128 rows x 128 cols).
__global__ __launch_bounds__(THREADS)
void reduce_k(const float* __restrict__ partials, float* __restrict__ out)
{
    __shared__ float sT[128][132];   // stride 132: 16B-aligned rows, banks ok

    const int b    = blockIdx.x;
    const int tile = b >> 1;
    const int h    = b & 1;                       // m-half within the 256-row tile
    const int m_idx = tile / NTILE_N;
    const int nb    = tile % NTILE_N;
    const int m0 = m_idx * BM + h * 128;
    const int n0 = nb * BN;
    const int u  = threadIdx.x;

    const float* base = partials + (size_t)tile * KSPLIT * TILE_ELEMS;

    // phase 1: sum partials for this half's 16384 floats, scatter into sT
    #pragma unroll
    for (int it = 0; it < 16; ++it) {
        int idx = it * 256 + u;                   // [0, 4096) f32x4-chunks
        int c   = idx >> 7;                       // [0,32)
        int tl  = idx & 127;
        int t   = (tl & 63) | (h << 6) | ((tl & 64) << 1);  // threads with wave&1==h
        int off = c * 1024 + t * 4;
        f32x4 s = *(const f32x4*)(base + off);
        s += *(const f32x4*)(base + TILE_ELEMS + off);
        s += *(const f32x4*)(base + 2 * TILE_ELEMS + off);
        s += *(const f32x4*)(base + 3 * TILE_ELEMS + off);
        int i = c >> 3, j = (c >> 2) & 1, q = c & 3;
        int lane = t & 63, wave = t >> 6;
        int mrow = i * 32 + (lane >> 5) * 4 + 8 * q;        // [0,128) within half
        int ncol = (wave >> 1) * 64 + j * 32 + (lane & 31);
        sT[mrow + 0][ncol] = s[0];
        sT[mrow + 1][ncol] = s[1];
        sT[mrow + 2][ncol] = s[2];
        sT[mrow + 3][ncol] = s[3];
    }
    __syncthreads();

    // phase 2: coalesced row-major writeout, 16B per lane
    #pragma unroll
    for (int it = 0; it < 16; ++it) {
        int idx = it * 256 + u;                   // [0, 4096)
        int row = idx >> 5;                       // 32 f32x4 per 128-col row
        int c4  = (idx & 31) * 4;
        f32x4 v = *(const f32x4*)&sT[row][c4];
        *(f32x4*)(out + (size_t)(m0 + row) * N_DIM + n0 + c4) = v;
    }
}

extern "C" void kernel_launch(void* const* d_in, const int* in_sizes, int n_in,
                              void* d_out, int out_size, void* d_ws, size_t ws_size,
                              hipStream_t stream) {
    (void)in_sizes; (void)n_in; (void)out_size;
    const float* x      = (const float*)d_in[0];
    const int*   wpck   = (const int*)d_in[1];
    const float* scales = (const float*)d_in[2];
    float*       out    = (float*)d_out;

    const size_t XW_BYTES   = (size_t)M_DIM * K_DIM * 2;                        // 4 MB
    const size_t PART_OFF   = XW_BYTES;
    const size_t PART_BYTES = (size_t)NTILES * KSPLIT * TILE_ELEMS * 4;         // 90.2 MB

    if (ws_size >= PART_OFF + PART_BYTES) {
        unsigned short* xw  = (unsigned short*)d_ws;
        float* part = (float*)((char*)d_ws + PART_OFF);
        cvt_x<<<(M_DIM * K_DIM) / (THREADS * 4), THREADS, 0, stream>>>(x, xw);
        dq_gemm<KSPLIT, true><<<NTILES * KSPLIT, THREADS, 0, stream>>>(
            xw, x, wpck, scales, out, part);
        reduce_k<<<NTILES * 2, THREADS, 0, stream>>>(part, out);
    } else if (ws_size >= XW_BYTES) {
        unsigned short* xw = (unsigned short*)d_ws;
        cvt_x<<<(M_DIM * K_DIM) / (THREADS * 4), THREADS, 0, stream>>>(x, xw);
        dq_gemm<1, true><<<NTILES, THREADS, 0, stream>>>(
            xw, x, wpck, scales, out, nullptr);
    } else {
        dq_gemm<1, false><<<NTILES, THREADS, 0, stream>>>(
            nullptr, x, wpck, scales, out, nullptr);
    }
}